// Round 1
// baseline (46.287 us; speedup 1.0000x reference)
//
#include <hip/hip_runtime.h>
#include <math.h>

#define NB 4096
#define INDIM 640
#define OUTDIM 64
#define EPSV 1e-6f

// ---------------------------------------------------------------------------
// K1: unscramble weight_v into w2[o][k] (o-major, contiguous in k) and compute
//     nw2[o] = sum_k w2[o][k]^2.
// Scramble closed form: w[o,i] = weight_v[i%64][o*10 + i/64]  (640 = 64*10)
// One block per output column o, 64 threads (one wave).
// ---------------------------------------------------------------------------
__global__ __launch_bounds__(64) void prep_w(const float* __restrict__ wv,
                                             float* __restrict__ w2,
                                             float* __restrict__ nw2) {
    int o = blockIdx.x;
    int t = threadIdx.x;  // 0..63  == k % 64
    float s = 0.f;
#pragma unroll
    for (int j = 0; j < 10; ++j) {          // j == k / 64
        float v = wv[t * 640 + o * 10 + j]; // weight_v[k%64][o*10 + k/64]
        w2[o * 640 + t + 64 * j] = v;       // coalesced write
        s += v * v;
    }
#pragma unroll
    for (int d = 32; d; d >>= 1) s += __shfl_xor(s, d);
    if (t == 0) nw2[o] = s;
}

// ---------------------------------------------------------------------------
// K2: per-row inv-norm of (x + eps) and normalized sum(x^2).
// One wave per row; coalesced scalar loads (lane l reads k = l + 64j).
// ---------------------------------------------------------------------------
__global__ __launch_bounds__(256) void row_norms(const float* __restrict__ x,
                                                 float* __restrict__ inv,
                                                 float* __restrict__ nx2) {
    int r = blockIdx.x * 4 + (threadIdx.x >> 6);
    int l = threadIdx.x & 63;
    const float* xr = x + r * 640;
    float s1 = 0.f, s2 = 0.f;
#pragma unroll
    for (int j = 0; j < 10; ++j) {
        float v = xr[l + 64 * j];
        float ve = v + EPSV;
        s1 += ve * ve;   // ||x + eps||^2  (matches torch.norm(x + 1e-6))
        s2 += v * v;     // ||x||^2
    }
#pragma unroll
    for (int d = 32; d; d >>= 1) {
        s1 += __shfl_xor(s1, d);
        s2 += __shfl_xor(s2, d);
    }
    if (l == 0) {
        float iv = rsqrtf(s1);
        inv[r] = iv;
        nx2[r] = s2 * iv * iv;  // ||xn||^2
    }
}

// ---------------------------------------------------------------------------
// K3: main GEMM-like kernel. dot[b][o] = x[b,:] . w2[o,:], then
//     out[b,o] = temp * sqrt(nx2[b] - 2*dot*inv[b] + nw2[o]).
// 128 blocks x 256 threads; 32 rows/block; K chunked at 160; LDS-staged
// x (32x164 padded) and w (64x164 padded); thread tile TM=2 rows x TN=4 cols
// with cols c = tx + 16j (avoids 8-way LDS bank conflict of contiguous cols).
// ---------------------------------------------------------------------------
__global__ __launch_bounds__(256) void main_kernel(
    const float* __restrict__ x, const float* __restrict__ w2,
    const float* __restrict__ nw2, const float* __restrict__ inv,
    const float* __restrict__ nx2, const float* __restrict__ temp,
    float* __restrict__ out) {
    // padded stride 164 floats (656 B: 16B-aligned rows, bank-spread)
    __shared__ float xs[32 * 164];
    __shared__ float ws[64 * 164];

    int tid = threadIdx.x;
    int tx = tid & 15;        // col group
    int ty = tid >> 4;        // row group (0..15) -> rows 2*ty, 2*ty+1
    int row0 = blockIdx.x * 32;

    float acc[2][4] = {{0.f, 0.f, 0.f, 0.f}, {0.f, 0.f, 0.f, 0.f}};

    for (int ch = 0; ch < 4; ++ch) {
        int kc = ch * 160;
        // stage x chunk: 32 rows x 160 = 1280 float4-quads
        for (int i = tid; i < 1280; i += 256) {
            int r = i / 40, kq = i % 40;
            const float4 v =
                *(const float4*)&x[(row0 + r) * 640 + kc + kq * 4];
            *(float4*)&xs[r * 164 + kq * 4] = v;
        }
        // stage w chunk: 64 cols x 160 = 2560 quads
        for (int i = tid; i < 2560; i += 256) {
            int c = i / 40, kq = i % 40;
            const float4 v = *(const float4*)&w2[c * 640 + kc + kq * 4];
            *(float4*)&ws[c * 164 + kq * 4] = v;
        }
        __syncthreads();

#pragma unroll 8
        for (int kq = 0; kq < 40; ++kq) {
            int k = kq * 4;
            float4 x0 = *(const float4*)&xs[(2 * ty) * 164 + k];
            float4 x1 = *(const float4*)&xs[(2 * ty + 1) * 164 + k];
#pragma unroll
            for (int j = 0; j < 4; ++j) {
                float4 wv = *(const float4*)&ws[(tx + 16 * j) * 164 + k];
                acc[0][j] += x0.x * wv.x + x0.y * wv.y + x0.z * wv.z + x0.w * wv.w;
                acc[1][j] += x1.x * wv.x + x1.y * wv.y + x1.z * wv.z + x1.w * wv.w;
            }
        }
        __syncthreads();
    }

    float tempv = temp[0];
#pragma unroll
    for (int m = 0; m < 2; ++m) {
        int r = row0 + 2 * ty + m;
        float iv = inv[r];
        float nx = nx2[r];
#pragma unroll
        for (int j = 0; j < 4; ++j) {
            int c = tx + 16 * j;
            float d2 = nx - 2.f * acc[m][j] * iv + nw2[c];
            out[r * 64 + c] = tempv * sqrtf(fmaxf(d2, 0.f));
        }
    }
}

extern "C" void kernel_launch(void* const* d_in, const int* in_sizes, int n_in,
                              void* d_out, int out_size, void* d_ws, size_t ws_size,
                              hipStream_t stream) {
    const float* x = (const float*)d_in[0];     // [4096, 640]
    const float* wv = (const float*)d_in[1];    // [64, 640]
    const float* temp = (const float*)d_in[2];  // [1]
    float* out = (float*)d_out;                 // [4096, 64]

    float* wsf = (float*)d_ws;
    float* w2 = wsf;            // 40960 floats
    float* nw2 = wsf + 40960;   // 64
    float* inv = wsf + 41024;   // 4096
    float* nx2 = wsf + 45120;   // 4096

    prep_w<<<64, 64, 0, stream>>>(wv, w2, nw2);
    row_norms<<<1024, 256, 0, stream>>>(x, inv, nx2);
    main_kernel<<<128, 256, 0, stream>>>(x, w2, nw2, inv, nx2, temp, out);
}

// Round 2
// 20.913 us; speedup vs baseline: 2.2134x; 2.2134x over previous
//
#include <hip/hip_runtime.h>
#include <math.h>

#define NBROWS 4096
#define INDIM 640
#define OUTDIM 64
#define EPSV 1e-6f

typedef short bf16x8 __attribute__((ext_vector_type(8)));
typedef float f32x4 __attribute__((ext_vector_type(4)));

// round-to-nearest-even f32 -> bf16 bits
static __device__ inline short f2bf(float f) {
    unsigned int u = __builtin_bit_cast(unsigned int, f);
    unsigned int r = u + 0x7FFFu + ((u >> 16) & 1u);
    return (short)(r >> 16);
}

// ---------------------------------------------------------------------------
// K1: unscramble weight_v (w[o,i] = weight_v[i%64][o*10 + i/64], 640=64*10),
// emit bf16 B-fragments in MFMA order + nw2[o] = ||w_o||^2 (f32 exact).
// Fragment map (my sigma, consistent with A): element (col o, k) lives at
//   kstep = k>>5, ctile = o>>4, lane = (o&15) | (((k>>3)&3)<<4), elem = k&7
//   wfrag[((kstep*4 + ctile)*64 + lane)*8 + elem]
// One block per o, 64 threads (t = k%64).
// ---------------------------------------------------------------------------
__global__ __launch_bounds__(64) void prep_w(const float* __restrict__ wv,
                                             short* __restrict__ wfrag,
                                             float* __restrict__ nw2) {
    int o = blockIdx.x;
    int t = threadIdx.x;  // k % 64
    float s = 0.f;
#pragma unroll
    for (int j = 0; j < 10; ++j) {          // j = k / 64
        float v = wv[t * 640 + o * 10 + j]; // weight_v[k%64][o*10 + k/64]
        int k = t + 64 * j;
        int lane = (o & 15) | (((k >> 3) & 3) << 4);
        wfrag[(((k >> 5) * 4 + (o >> 4)) * 64 + lane) * 8 + (k & 7)] = f2bf(v);
        s += v * v;
    }
#pragma unroll
    for (int d = 32; d; d >>= 1) s += __shfl_xor(s, d);
    if (t == 0) nw2[o] = s;
}

// ---------------------------------------------------------------------------
// K2: per-row inv-norm of (x+eps) and normalized ||xn||^2. One wave per row.
// ---------------------------------------------------------------------------
__global__ __launch_bounds__(256) void row_norms(const float* __restrict__ x,
                                                 float* __restrict__ inv,
                                                 float* __restrict__ nx2) {
    int r = blockIdx.x * 4 + (threadIdx.x >> 6);
    int l = threadIdx.x & 63;
    const float* xr = x + r * 640;
    float s1 = 0.f, s2 = 0.f;
#pragma unroll
    for (int j = 0; j < 10; ++j) {
        float v = xr[l + 64 * j];
        float ve = v + EPSV;
        s1 += ve * ve;
        s2 += v * v;
    }
#pragma unroll
    for (int d = 32; d; d >>= 1) {
        s1 += __shfl_xor(s1, d);
        s2 += __shfl_xor(s2, d);
    }
    if (l == 0) {
        float iv = rsqrtf(s1);
        inv[r] = iv;
        nx2[r] = s2 * iv * iv;
    }
}

// ---------------------------------------------------------------------------
// K3: partial dots via MFMA. One wave per (rowtile 16, coltile 16, K-seg).
// bid = (kseg*4 + ct)*256 + rt  -> same-rt jobs share an XCD (rt % 8).
// A built in-register from global f32 x (2x float4 per kstep, cvt to bf16).
// B read as contiguous b128 from pre-packed wfrag.
// C/D layout (HW-verified): col = lane&15, row = (lane>>4)*4 + reg.
// ---------------------------------------------------------------------------
template <int KSTEPS>
__global__ __launch_bounds__(64) void mfma_dots(const float* __restrict__ x,
                                                const short* __restrict__ wfrag,
                                                float* __restrict__ dotp) {
    int l = threadIdx.x, lm = l & 15, lg = l >> 4;
    int bid = blockIdx.x;
    int rt = bid & 255;
    int cc = bid >> 8;
    int ct = cc & 3, kseg = cc >> 2;
    int ks0 = kseg * KSTEPS;

    const float* xr = x + (rt * 16 + lm) * 640 + ks0 * 32 + lg * 8;
    const bf16x8* wf = (const bf16x8*)wfrag;

    f32x4 acc = {0.f, 0.f, 0.f, 0.f};
#pragma unroll
    for (int s = 0; s < KSTEPS; ++s) {
        float4 a0 = *(const float4*)(xr + s * 32);
        float4 a1 = *(const float4*)(xr + s * 32 + 4);
        bf16x8 a;
        a[0] = f2bf(a0.x); a[1] = f2bf(a0.y); a[2] = f2bf(a0.z); a[3] = f2bf(a0.w);
        a[4] = f2bf(a1.x); a[5] = f2bf(a1.y); a[6] = f2bf(a1.z); a[7] = f2bf(a1.w);
        bf16x8 b = wf[((ks0 + s) * 4 + ct) * 64 + l];
        acc = __builtin_amdgcn_mfma_f32_16x16x32_bf16(a, b, acc, 0, 0, 0);
    }

    float* dp = dotp + kseg * (NBROWS * 64);
    int colo = ct * 16 + lm;
    int rbase = rt * 16 + lg * 4;
#pragma unroll
    for (int i = 0; i < 4; ++i) dp[(rbase + i) * 64 + colo] = acc[i];
}

// ---------------------------------------------------------------------------
// K4: combine partials + distance formula. 65536 threads x 4 outputs (float4).
// ---------------------------------------------------------------------------
__global__ __launch_bounds__(256) void epilogue(const float* __restrict__ dotp,
                                                const float* __restrict__ inv,
                                                const float* __restrict__ nx2,
                                                const float* __restrict__ nw2,
                                                const float* __restrict__ temp,
                                                float* __restrict__ out, int nseg) {
    int id = blockIdx.x * 256 + threadIdx.x;  // 0..65535
    int r = id >> 4, cq = id & 15;
    float4 d = *(const float4*)(dotp + r * 64 + cq * 4);
    if (nseg == 2) {
        float4 d2 = *(const float4*)(dotp + NBROWS * 64 + r * 64 + cq * 4);
        d.x += d2.x; d.y += d2.y; d.z += d2.z; d.w += d2.w;
    }
    float iv = inv[r], nx = nx2[r], tv = temp[0];
    float4 w4 = *(const float4*)(nw2 + cq * 4);
    float4 o;
    o.x = tv * sqrtf(fmaxf(nx - 2.f * d.x * iv + w4.x, 0.f));
    o.y = tv * sqrtf(fmaxf(nx - 2.f * d.y * iv + w4.y, 0.f));
    o.z = tv * sqrtf(fmaxf(nx - 2.f * d.z * iv + w4.z, 0.f));
    o.w = tv * sqrtf(fmaxf(nx - 2.f * d.w * iv + w4.w, 0.f));
    *(float4*)(out + r * 64 + cq * 4) = o;
}

extern "C" void kernel_launch(void* const* d_in, const int* in_sizes, int n_in,
                              void* d_out, int out_size, void* d_ws, size_t ws_size,
                              hipStream_t stream) {
    const float* x = (const float*)d_in[0];     // [4096, 640]
    const float* wv = (const float*)d_in[1];    // [64, 640]
    const float* temp = (const float*)d_in[2];  // [1]
    float* out = (float*)d_out;                 // [4096, 64]

    // workspace layout (bytes):
    //   dotp:  nseg * 4096*64*4   (1 or 2 MB)
    //   wfrag: 20*4*64*8 shorts = 81920 B
    //   nw2:   64 f, inv: 4096 f, nx2: 4096 f
    const size_t dot_elems = (size_t)NBROWS * 64;
    const size_t need2 = 2 * dot_elems * 4 + 81920 + (64 + 4096 + 4096) * 4;
    const int nseg = (ws_size >= need2) ? 2 : 1;

    char* wsb = (char*)d_ws;
    float* dotp = (float*)wsb;
    short* wfrag = (short*)(wsb + nseg * dot_elems * 4);
    float* nw2 = (float*)((char*)wfrag + 81920);
    float* inv = nw2 + 64;
    float* nx2 = inv + 4096;

    prep_w<<<64, 64, 0, stream>>>(wv, wfrag, nw2);
    row_norms<<<1024, 256, 0, stream>>>(x, inv, nx2);
    if (nseg == 2) {
        mfma_dots<10><<<2048, 64, 0, stream>>>(x, wfrag, dotp);
    } else {
        mfma_dots<20><<<1024, 64, 0, stream>>>(x, wfrag, dotp);
    }
    epilogue<<<256, 256, 0, stream>>>(dotp, inv, nx2, nw2, temp, out, nseg);
}

// Round 3
// 17.153 us; speedup vs baseline: 2.6985x; 1.2192x over previous
//
#include <hip/hip_runtime.h>
#include <math.h>

#define NBROWS 4096
#define INDIM 640
#define OUTDIM 64
#define EPSV 1e-6f

typedef short bf16x8 __attribute__((ext_vector_type(8)));
typedef float f32x4 __attribute__((ext_vector_type(4)));

// round-to-nearest-even f32 -> bf16 bits
static __device__ inline short f2bf(float f) {
    unsigned int u = __builtin_bit_cast(unsigned int, f);
    unsigned int r = u + 0x7FFFu + ((u >> 16) & 1u);
    return (short)(r >> 16);
}

// ---------------------------------------------------------------------------
// K1: unscramble weight_v (w[o,i] = weight_v[i%64][o*10 + i/64], 640=64*10),
// emit bf16 B-fragments in MFMA order + nw2[o] = ||w_o||^2 (f32 exact).
// Fragment sigma (consistent with A-side): element (col o, k):
//   kstep = k>>5, ctile = o>>4, lane = (o&15) | (((k>>3)&3)<<4), elem = k&7
//   wfrag[((kstep*4 + ctile)*64 + lane)*8 + elem]
// ---------------------------------------------------------------------------
__global__ __launch_bounds__(64) void prep_w(const float* __restrict__ wv,
                                             short* __restrict__ wfrag,
                                             float* __restrict__ nw2) {
    int o = blockIdx.x;
    int t = threadIdx.x;  // k % 64
    float s = 0.f;
#pragma unroll
    for (int j = 0; j < 10; ++j) {          // j = k / 64
        float v = wv[t * 640 + o * 10 + j]; // weight_v[k%64][o*10 + k/64]
        int k = t + 64 * j;
        int lane = (o & 15) | (((k >> 3) & 3) << 4);
        wfrag[(((k >> 5) * 4 + (o >> 4)) * 64 + lane) * 8 + (k & 7)] = f2bf(v);
        s += v * v;
    }
#pragma unroll
    for (int d = 32; d; d >>= 1) s += __shfl_xor(s, d);
    if (t == 0) nw2[o] = s;
}

// ---------------------------------------------------------------------------
// K2: fused norms + MFMA dots + distance epilogue.
// 256 blocks x 512 threads = 8 waves: wave w -> ct = w&3 (16-col tile),
// kh = w>>2 (K half, 320 each). Each wave: 16 rows x 320 k. x read ONCE.
// Norms from the same registers as the A-fragment (reduce over lg via
// shfl_xor 16/32, combine K-halves via LDS). kh=1 waves park acc in LDS;
// kh=0 waves combine, apply temp*sqrt(nx2 - 2*dot*inv + nw2), store.
// C/D layout (HW-verified): col = lane&15, row = (lane>>4)*4 + reg.
// ---------------------------------------------------------------------------
__global__ __launch_bounds__(512) void fused(const float* __restrict__ x,
                                             const short* __restrict__ wfrag,
                                             const float* __restrict__ nw2,
                                             const float* __restrict__ temp,
                                             float* __restrict__ out) {
    __shared__ f32x4 ldsacc[4][64];      // kh=1 accs, per ct per lane
    __shared__ float2 ldsn[2][4][16];    // (s1,s2) per kh, ct, row

    int tid = threadIdx.x;
    int l = tid & 63, lm = l & 15, lg = (l >> 4) & 3;
    int w = tid >> 6;
    int ct = w & 3, kh = w >> 2;
    int rt = blockIdx.x;

    const float* xr = x + (rt * 16 + lm) * 640 + kh * 320 + lg * 8;
    const bf16x8* wf = (const bf16x8*)wfrag;

    f32x4 acc = {0.f, 0.f, 0.f, 0.f};
    float s1 = 0.f, s2 = 0.f;
#pragma unroll
    for (int s = 0; s < 10; ++s) {
        float4 a0 = *(const float4*)(xr + s * 32);
        float4 a1 = *(const float4*)(xr + s * 32 + 4);
        bf16x8 a;
        a[0] = f2bf(a0.x); a[1] = f2bf(a0.y); a[2] = f2bf(a0.z); a[3] = f2bf(a0.w);
        a[4] = f2bf(a1.x); a[5] = f2bf(a1.y); a[6] = f2bf(a1.z); a[7] = f2bf(a1.w);
        float e0 = a0.x + EPSV, e1 = a0.y + EPSV, e2 = a0.z + EPSV, e3 = a0.w + EPSV;
        float e4 = a1.x + EPSV, e5 = a1.y + EPSV, e6 = a1.z + EPSV, e7 = a1.w + EPSV;
        s1 += e0*e0 + e1*e1 + e2*e2 + e3*e3 + e4*e4 + e5*e5 + e6*e6 + e7*e7;
        s2 += a0.x*a0.x + a0.y*a0.y + a0.z*a0.z + a0.w*a0.w
            + a1.x*a1.x + a1.y*a1.y + a1.z*a1.z + a1.w*a1.w;
        bf16x8 b = wf[((kh * 10 + s) * 4 + ct) * 64 + l];
        acc = __builtin_amdgcn_mfma_f32_16x16x32_bf16(a, b, acc, 0, 0, 0);
    }

    // reduce norm partials across lg (lanes sharing lm): xor bits 4,5
    s1 += __shfl_xor(s1, 16); s1 += __shfl_xor(s1, 32);
    s2 += __shfl_xor(s2, 16); s2 += __shfl_xor(s2, 32);
    if (lg == 0) ldsn[kh][ct][lm] = make_float2(s1, s2);
    if (kh == 1) ldsacc[ct][l] = acc;
    __syncthreads();

    if (kh == 0) {
        f32x4 a2 = ldsacc[ct][l];
        acc[0] += a2[0]; acc[1] += a2[1]; acc[2] += a2[2]; acc[3] += a2[3];
        float tv = temp[0];
        float nwv = nw2[ct * 16 + lm];
#pragma unroll
        for (int i = 0; i < 4; ++i) {
            int r = lg * 4 + i;
            float2 n0 = ldsn[0][ct][r];
            float2 n1 = ldsn[1][ct][r];
            float S1 = n0.x + n1.x;
            float S2 = n0.y + n1.y;
            float iv = rsqrtf(S1);
            float nx = S2 * iv * iv;
            float d2 = nx - 2.f * acc[i] * iv + nwv;
            out[(rt * 16 + r) * 64 + ct * 16 + lm] = tv * sqrtf(fmaxf(d2, 0.f));
        }
    }
}

extern "C" void kernel_launch(void* const* d_in, const int* in_sizes, int n_in,
                              void* d_out, int out_size, void* d_ws, size_t ws_size,
                              hipStream_t stream) {
    const float* x = (const float*)d_in[0];     // [4096, 640]
    const float* wv = (const float*)d_in[1];    // [64, 640]
    const float* temp = (const float*)d_in[2];  // [1]
    float* out = (float*)d_out;                 // [4096, 64]

    // workspace: wfrag (20*4*64*8 shorts = 81920 B) then nw2 (64 f32)
    short* wfrag = (short*)d_ws;
    float* nw2 = (float*)((char*)d_ws + 81920);

    prep_w<<<64, 64, 0, stream>>>(wv, wfrag, nw2);
    fused<<<256, 512, 0, stream>>>(x, wfrag, nw2, temp, out);
}